// Round 1
// baseline (131.048 us; speedup 1.0000x reference)
//
#include <hip/hip_runtime.h>
#include <hip/hip_bf16.h>

#define NB    2048
#define NUMK  128
#define NE    1024
#define HID   32
#define ROWLEN (NUMK + NE + 2)
#define CAP   24                 // padded slots per row (unique srcs + self)
#define ASTRIDE 136              // bf16 elems per Â row (128 + 8 pad)
#define X1STRIDE 72              // bf16 elems per x1T-half row (64 + 8 pad)
#define W2STRIDE 40              // (kept for reference; W2 frags now from global)
#define WSELF 1024               // widx of self-loop weight (1.0)
#define WPAD  1025               // widx of pad weight (0.0)
#define WVBASE 1026              // first vslot (chained dup merges)
#define MAXV  16

// Fused single-kernel version: each block redundantly rebuilds the CSR/dedup
// tables from edge_index (8 KB, L2-hot) into LDS overlays, so NOTHING is ever
// written to d_ws. Rationale: the rocprof top-5 was five 256 MiB
// fillBufferAligned dispatches (41 us each) — the harness's d_ws poison that
// exists only because the old build_csr kernel dirtied the workspace; plus we
// drop the serialized 1-block build launch. MFMA/main-path code is verbatim
// from the validated R12 kernel.
//
// slot encoding: src(7) | widx(11)<<7 | widx2(11)<<18 | prim(1)<<29
// vmeta[1+v] = a(11) | b(11)<<11 : vslot weight = w(a) + w(b); a may chain.
// Weights/signals are read DIRECTLY from the graph's Hx row (L1-hot, 4.6 KB).

using s8  = __attribute__((ext_vector_type(8))) short;   // 8 bf16 = 16 B
using s4v = __attribute__((ext_vector_type(4))) short;   // 4 bf16 = 8 B
using f4  = __attribute__((ext_vector_type(4))) float;
using fl4 = __attribute__((ext_vector_type(4))) float;

static __device__ __forceinline__ unsigned short f2bf(float f) {
    unsigned u = __float_as_uint(f);
    unsigned r = (u + 0x7fffu + ((u >> 16) & 1u)) >> 16;   // RNE
    return (unsigned short)r;
}

// resolve a weight index (raw eid / WSELF / WPAD / vslot chain)
static __device__ __forceinline__ float wload(const float* __restrict__ rowp,
                                              unsigned idx,
                                              const unsigned* vmeta) {
    float w = 0.f;
    while (idx >= (unsigned)WVBASE) {                  // rare: >=3-dup chains
        const unsigned e = vmeta[1 + (idx - (unsigned)WVBASE)];
        const unsigned b = e >> 11;
        w += (b < 1024u) ? rowp[NUMK + b] : (b == (unsigned)WSELF ? 1.0f : 0.0f);
        idx = e & 0x7FFu;
    }
    w += (idx < 1024u) ? rowp[NUMK + idx] : (idx == (unsigned)WSELF ? 1.0f : 0.0f);
    return w;
}

// ---------------------------------------------------------------------------
// One block (512 thr = 8 waves) per graph. LDS ~40.5 KB.
// Build scratch overlays regions that are dead during the build phase:
//   psl[128][24] -> Ab[0..12288B)     pk[1024] -> Ab[12288..16384B)
//   cnt[128]     -> degv              incl[128] -> a0s
//   roff[129]    -> x1h[0..516B)      cur[128]  -> x1h[528..1040B)
// ---------------------------------------------------------------------------
__global__ __launch_bounds__(512, 6) void gcn_fused_kernel(
    const float* __restrict__ Hx,
    const int*   __restrict__ ei,
    const float* __restrict__ W1, const float* __restrict__ b1,
    const float* __restrict__ W2, const float* __restrict__ b2,
    const float* __restrict__ W3, const float* __restrict__ b3,
    float* __restrict__ out)
{
    __shared__ __align__(16) short Ab[NUMK * ASTRIDE];    // 34816 B
    __shared__ __align__(16) short x1h[HID * X1STRIDE];   //  4608 B
    __shared__ float degv[NUMK];                          //   512 B
    __shared__ float a0s[NUMK];                           //   512 B
    __shared__ unsigned vmeta[1 + MAXV];                  //    68 B
    __shared__ unsigned vcs;

    const int tid = threadIdx.x;                // 0..511
    const int row = tid >> 2, l4 = tid & 3;     // 128 rows x 4 lanes
    const int wv = tid >> 6, lane = tid & 63;
    const int l = lane & 15, q = lane >> 4;
    const float* rowp = Hx + (size_t)blockIdx.x * ROWLEN;

    // ---- build-phase LDS overlays ----
    unsigned* psl  = (unsigned*)Ab;             // [128*CAP]
    unsigned* pk   = (unsigned*)Ab + NUMK * CAP;// [1024]
    unsigned* cnt  = (unsigned*)degv;           // [128]
    unsigned* incl = (unsigned*)a0s;            // [128]
    unsigned* roff = (unsigned*)x1h;            // [129]
    unsigned* cur  = (unsigned*)x1h + 132;      // [128]

    // ---- B-phase 0: edge loads (L2-hot after round 1) + init ----
    const int e0 = tid, e1 = tid + 512;
    const int s0 = ei[e0]      & (NUMK - 1);
    const int d0 = ei[NE + e0] & (NUMK - 1);
    const int s1 = ei[e1]      & (NUMK - 1);
    const int d1 = ei[NE + e1] & (NUMK - 1);

    if (tid < NUMK) cnt[tid] = 0u;
    if (tid == 0) vcs = 0u;
    __syncthreads();                                   // BB1

    atomicAdd(&cnt[d0], 1u);
    atomicAdd(&cnt[d1], 1u);
    __syncthreads();                                   // BB2

    if (tid < NUMK) {                        // exclusive scan (2 wave scans)
        unsigned v = cnt[tid];
        #pragma unroll
        for (int d = 1; d < 64; d <<= 1) {
            unsigned u = __shfl_up(v, d, 64);
            if ((tid & 63) >= d) v += u;
        }
        incl[tid] = v;
    }
    __syncthreads();                                   // BB3
    if (tid < NUMK) {
        const unsigned base = (tid >= 64) ? incl[63] : 0u;
        const unsigned off  = base + incl[tid] - cnt[tid];
        roff[tid] = off; cur[tid] = off;
    }
    if (tid == 0) roff[NUMK] = (unsigned)NE;
    __syncthreads();                                   // BB4

    {
        const unsigned p0 = atomicAdd(&cur[d0], 1u);
        pk[p0] = (unsigned)s0 | ((unsigned)e0 << 16);
        const unsigned p1 = atomicAdd(&cur[d1], 1u);
        pk[p1] = (unsigned)s1 | ((unsigned)e1 << 16);
    }
    __syncthreads();                                   // BB5

    if (tid < NUMK) {                        // per-row dedup into slots
        int np = 0;
        unsigned* prow = &psl[tid * CAP];
        auto addOrMerge = [&](unsigned s, unsigned eid) {
            int j = -1;
            for (int i = 0; i < np; ++i)
                if ((prow[i] & 127u) == s) { j = i; break; }
            if (j >= 0) {
                const unsigned slot = prow[j];
                const unsigned w2x = (slot >> 18) & 0x7FFu;
                if (w2x == (unsigned)WPAD) {
                    prow[j] = (slot & ~(0x7FFu << 18)) | (eid << 18);
                } else {
                    const unsigned v = atomicAdd(&vcs, 1u);
                    if (v < (unsigned)MAXV) {
                        vmeta[1 + v] = w2x | (eid << 11);
                        prow[j] = (slot & ~(0x7FFu << 18))
                                | (((unsigned)WVBASE + v) << 18);
                    }
                }
            } else if (np < CAP) {
                prow[np++] = s | (eid << 7)
                           | ((unsigned)WPAD << 18) | (1u << 29);
            }
        };
        const unsigned k0 = roff[tid], k1 = roff[tid + 1];
        for (unsigned k = k0; k < k1; ++k)
            addOrMerge(pk[k] & 127u, pk[k] >> 16);
        addOrMerge((unsigned)tid, (unsigned)WSELF);    // self-loop, w = 1
        for (int i = np; i < CAP; ++i)                 // pads: w = 0, prim = 0
            prow[i] = ((unsigned)WPAD << 7) | ((unsigned)WPAD << 18);
    }
    __syncthreads();                                   // BB6

    // ---- own slots out of LDS before Ab overwrites psl ----
    unsigned su[6];
    #pragma unroll
    for (int e = 0; e < 6; ++e) su[e] = psl[row * CAP + l4 * 6 + e];
    __syncthreads();                                   // BB7

    // ---- zero A^ ----
    for (int t2 = tid; t2 < (NUMK * ASTRIDE) / 8; t2 += 512)
        *(s8*)&Ab[t2 * 8] = (s8)0;

    // ---- P2: merged slot weights from GLOBAL + deg -> dinv ----
    float nvr[6];
    {
        float d = 0.f;
        #pragma unroll
        for (int e = 0; e < 6; ++e) {
            const unsigned u = su[e];
            nvr[e] = wload(rowp, (u >> 7) & 0x7FFu, vmeta)
                   + wload(rowp, (u >> 18) & 0x7FFu, vmeta);
            d += nvr[e];
        }
        d += __shfl_xor(d, 1, 4);
        d += __shfl_xor(d, 2, 4);
        if (l4 == 0) degv[row] = rsqrtf(d);            // deg >= 1 (self w=1)
    }
    __syncthreads();                                   // B1

    // ---- P4: norms + A^ scatter (own row) + a0 = A^·p ----
    {
        const float dr = degv[row];
        float acc = 0.f;
        #pragma unroll
        for (int e = 0; e < 6; ++e) {
            const unsigned u = su[e];
            const int s = (int)(u & 127u);
            const float nv = (u >> 29) ? dr * degv[s] * nvr[e] : 0.f;
            if (u >> 29) Ab[row * ASTRIDE + s] = (short)f2bf(nv);
            nvr[e] = nv;
            acc = fmaf(nv, rowp[s], acc);              // p[s] from L1-hot row
        }
        acc += __shfl_xor(acc, 1, 4);
        acc += __shfl_xor(acc, 2, 4);
        if (l4 == 0) a0s[row] = acc;
    }
    __syncthreads();                                   // B2

    // ---- layer-2 propagate: a1 = A^ @ x1, x1 built in two 64-K halves ----
    f4 accm0 = {0.f,0.f,0.f,0.f}, accm1 = {0.f,0.f,0.f,0.f};
    const int arow = (wv << 4) + l;                    // wave-exclusive A^ row
    #pragma unroll
    for (int half = 0; half < 2; ++half) {
        {   // build x1h half: x1h[j][k] = relu(a0[64h+k]*w1[j]+b1[j])
            const int jj = tid >> 4;                   // x1T row 0..31
            const float w1j = W1[jj], b1j = b1[jj];    // L2-hot
            const int kk = (tid & 15) << 2;            // 0..60
            const fl4 av = *(const fl4*)&a0s[(half << 6) + kk];
            union { unsigned u[2]; s4v v; } P;
            P.u[0] = (unsigned)f2bf(fmaxf(fmaf(av[0], w1j, b1j), 0.f))
                   | ((unsigned)f2bf(fmaxf(fmaf(av[1], w1j, b1j), 0.f)) << 16);
            P.u[1] = (unsigned)f2bf(fmaxf(fmaf(av[2], w1j, b1j), 0.f))
                   | ((unsigned)f2bf(fmaxf(fmaf(av[3], w1j, b1j), 0.f)) << 16);
            *(s4v*)&x1h[jj * X1STRIDE + kk] = P.v;
        }
        __syncthreads();                               // B3 / B5
        #pragma unroll
        for (int ks2 = 0; ks2 < 2; ++ks2) {
            const int kloc = (ks2 << 5) + (q << 3);
            const s8 A  = *(const s8*)&Ab[arow * ASTRIDE + (half << 6) + kloc];
            const s8 B0 = *(const s8*)&x1h[l * X1STRIDE + kloc];
            const s8 B1 = *(const s8*)&x1h[(16 + l) * X1STRIDE + kloc];
            accm0 = __builtin_amdgcn_mfma_f32_16x16x32_bf16(A, B0, accm0, 0, 0, 0);
            accm1 = __builtin_amdgcn_mfma_f32_16x16x32_bf16(A, B1, accm1, 0, 0, 0);
        }
        if (half == 0) __syncthreads();                // B4 (x1h reads done)
    }

    // ---- a1 -> own A^ rows (same wave, DS in-order: no barrier) ----
    short* a1w = &Ab[(wv << 4) * ASTRIDE];             // 16 rows x W2STRIDE
    #pragma unroll
    for (int r = 0; r < 4; ++r) {
        const int tr = (q << 2) + r;
        a1w[tr * W2STRIDE + l]      = (short)f2bf(accm0[r]);
        a1w[tr * W2STRIDE + 16 + l] = (short)f2bf(accm1[r]);
    }

    // ---- P7: x2 = relu(a1@W2+b2); s = x2@W3 ----
    // W2^T B-fragments built at point-of-use from L2-hot global W2 (4 KB):
    // Bw0[j] = bf16(W2[(q*8+j)*32 + l]), Bw1[j] = bf16(W2[(q*8+j)*32 + 16+l])
    {
        s8 Bw0, Bw1;
        #pragma unroll
        for (int j2 = 0; j2 < 8; ++j2) {
            const int krow = (q << 3) + j2;
            Bw0[j2] = (short)f2bf(W2[(krow << 5) + l]);
            Bw1[j2] = (short)f2bf(W2[(krow << 5) + 16 + l]);
        }
        const s8 A0 = *(const s8*)&a1w[l * W2STRIDE + (q << 3)];
        f4 ac20 = {0.f,0.f,0.f,0.f}, ac21 = {0.f,0.f,0.f,0.f};
        ac20 = __builtin_amdgcn_mfma_f32_16x16x32_bf16(A0, Bw0, ac20, 0, 0, 0);
        ac21 = __builtin_amdgcn_mfma_f32_16x16x32_bf16(A0, Bw1, ac21, 0, 0, 0);

        const float b2a = b2[l], b2b = b2[l + 16];     // L2-hot, loaded at use
        const float w3a = W3[l], w3b = W3[l + 16];
        float* sbuf = degv;                            // dinv dead after P4
        #pragma unroll
        for (int r = 0; r < 4; ++r) {
            const float v0 = fmaxf(ac20[r] + b2a, 0.f);
            const float v1 = fmaxf(ac21[r] + b2b, 0.f);
            float sv = v0 * w3a + v1 * w3b;
            #pragma unroll
            for (int m = 1; m < 16; m <<= 1) sv += __shfl_xor(sv, m, 16);
            if (l == 0) sbuf[(wv << 4) + (q << 2) + r] = sv;
        }
    }
    __syncthreads();                                   // B6

    // ---- P8: out = A^·s (norms + slots from regs) ----
    {
        float* sbuf = degv;
        float acc8 = 0.f;
        #pragma unroll
        for (int e = 0; e < 6; ++e)
            acc8 = fmaf(nvr[e], sbuf[su[e] & 127u], acc8);
        acc8 += __shfl_xor(acc8, 1, 4);
        acc8 += __shfl_xor(acc8, 2, 4);
        if (l4 == 0) out[(size_t)blockIdx.x * NUMK + row] = acc8 + b3[0];
    }
}

extern "C" void kernel_launch(void* const* d_in, const int* in_sizes, int n_in,
                              void* d_out, int out_size, void* d_ws, size_t ws_size,
                              hipStream_t stream) {
    const float* Hx = (const float*)d_in[0];
    const int*   ei = (const int*)d_in[1];
    const float* W1 = (const float*)d_in[2];
    const float* b1 = (const float*)d_in[3];
    const float* W2 = (const float*)d_in[4];
    const float* b2 = (const float*)d_in[5];
    const float* W3 = (const float*)d_in[6];
    const float* b3 = (const float*)d_in[7];
    float* out = (float*)d_out;

    // d_ws intentionally untouched: no workspace writes -> no 256 MiB
    // poison-restore in the timed path, and no serialized build kernel.
    (void)d_ws; (void)ws_size;
    gcn_fused_kernel<<<NB, 512, 0, stream>>>(Hx, ei, W1, b1, W2, b2, W3, b3, out);
}

// Round 2
// 118.700 us; speedup vs baseline: 1.1040x; 1.1040x over previous
//
#include <hip/hip_runtime.h>
#include <hip/hip_bf16.h>

#define NB    2048
#define NUMK  128
#define NE    1024
#define HID   32
#define ROWLEN (NUMK + NE + 2)
#define X1STRIDE 72              // bf16 elems per x1T-half row (64 + 8 pad)
#define A1STRIDE 40              // bf16 elems per a1 row (32 + 8; 80 B rows = 16B-aligned)
#define QS 8192.0f               // fixed-point scale 2^13; max packed half-sum 4.0*8192 < 2^15
#define QI (1.0f/8192.0f)

// Round-2 design: single kernel, PARALLEL per-block build (no serial dedup).
//  - Â accumulated densely in LDS as packed u16 fixed-point (2 entries / u32)
//    via atomicAdd; packed halves can't carry (each sum < 2^15). Converted
//    IN PLACE to bf16 (same 32 KB buffer the MFMA needs) -> no extra LDS.
//  - deg and a0 = Â·p are fp32 LDS atomic scatter passes (all 512 threads).
//  - layer-3 out = Â·s is edge-parallel in fp32 (norms nv0/nv1 kept in regs
//    from the build pass) -> final propagate stays fp32-accurate as in R12.
//  - Â uses XOR swizzle byte^=((row&7)<<4) applied identically at atomic
//    write, in-place convert, and MFMA read (stride 256 B would otherwise be
//    a 16-way bank conflict).
//  - d_ws untouched (the 256 MiB poison fill is unconditional anyway).
// MFMA section (x1 build, a1 MFMA, P7) verbatim from the validated R12 code,
// except Â stride 136->128(+swizzle) and a1 -> separate buffer (Â must stay
// intact for layer 3).

using s8    = __attribute__((ext_vector_type(8))) short;   // 8 bf16 = 16 B
using s4v   = __attribute__((ext_vector_type(4))) short;   // 4 bf16 = 8 B
using f4    = __attribute__((ext_vector_type(4))) float;
using fl4   = __attribute__((ext_vector_type(4))) float;
using u32x4 = __attribute__((ext_vector_type(4))) unsigned;

static __device__ __forceinline__ unsigned short f2bf(float f) {
    unsigned u = __float_as_uint(f);
    unsigned r = (u + 0x7fffu + ((u >> 16) & 1u)) >> 16;   // RNE
    return (unsigned short)r;
}

__global__ __launch_bounds__(512, 6) void gcn_fused_kernel(
    const float* __restrict__ Hx,
    const int*   __restrict__ ei,
    const float* __restrict__ W1, const float* __restrict__ b1,
    const float* __restrict__ W2, const float* __restrict__ b2,
    const float* __restrict__ W3, const float* __restrict__ b3,
    float* __restrict__ out)
{
    __shared__ __align__(16) short Ab[NUMK * 128];          // 32768 B (u32 alias)
    __shared__ __align__(16) short a1b[NUMK * A1STRIDE];    // 10240 B
    __shared__ __align__(16) short x1h[HID * X1STRIDE];     //  4608 B
    __shared__ float degv[NUMK];                            //   512 B (deg -> dinv)
    __shared__ float a0s[NUMK];                             //   512 B (a0 -> outacc)
    __shared__ float sbuf[NUMK];                            //   512 B (layer-3 s)
    // total 49,152 B -> 3 blocks/CU at launch_bounds(512,6)

    const int tid = threadIdx.x;                // 0..511
    const int row = tid >> 2, l4 = tid & 3;     // 128 rows x 4 lanes
    const int wv = tid >> 6, lane = tid & 63;
    const int l = lane & 15, q = lane >> 4;
    const float* rowp = Hx + (size_t)blockIdx.x * ROWLEN;
    unsigned* Apk = (unsigned*)Ab;
    char*     Abc = (char*)Ab;

    // ---- phase 0: edge/weight loads (prefetch), zero Apk, init deg/a0 ----
    const int e0 = tid, e1 = tid + 512;
    const int s0 = ei[e0]      & (NUMK - 1);
    const int d0 = ei[NE + e0] & (NUMK - 1);
    const int s1 = ei[e1]      & (NUMK - 1);
    const int d1 = ei[NE + e1] & (NUMK - 1);
    const float w0 = rowp[NUMK + e0];
    const float w1 = rowp[NUMK + e1];
    const float p0 = rowp[s0], p1 = rowp[s1];          // p[src], L1-hot row

    {
        const u32x4 z4 = {0u, 0u, 0u, 0u};
        #pragma unroll
        for (int c = 0; c < 4; ++c)
            *(u32x4*)&Apk[(tid << 2) + (c << 11)] = z4;
    }
    if (tid < NUMK) { degv[tid] = 1.0f; a0s[tid] = 0.f; }  // deg incl. self w=1
    __syncthreads();                                   // BB1

    // ---- pass A: deg scatter ----
    atomicAdd(&degv[d0], w0);
    atomicAdd(&degv[d1], w1);
    __syncthreads();                                   // BB2
    if (tid < NUMK) degv[tid] = rsqrtf(degv[tid]);     // deg >= 1 always
    __syncthreads();                                   // BB3

    // ---- pass B: norms -> Â (fixed-point packed) + a0 scatter (fp32) ----
    const float nv0 = degv[s0] * w0 * degv[d0];
    const float nv1 = degv[s1] * w1 * degv[d1];
    {
        const unsigned q0 = __float2uint_rn(nv0 * QS);
        const unsigned q1 = __float2uint_rn(nv1 * QS);
        atomicAdd(&Apk[((d0 << 6) + (s0 >> 1)) ^ ((d0 & 7) << 2)],
                  q0 << ((s0 & 1) << 4));
        atomicAdd(&Apk[((d1 << 6) + (s1 >> 1)) ^ ((d1 & 7) << 2)],
                  q1 << ((s1 & 1) << 4));
        atomicAdd(&a0s[d0], nv0 * p0);
        atomicAdd(&a0s[d1], nv1 * p1);
        if (tid < NUMK) {                              // self-loop terms
            const float dq = degv[tid];
            const float nvs = dq * dq;                 // w = 1
            atomicAdd(&Apk[((tid << 6) + (tid >> 1)) ^ ((tid & 7) << 2)],
                      __float2uint_rn(nvs * QS) << ((tid & 1) << 4));
            atomicAdd(&a0s[tid], nvs * rowp[tid]);
        }
    }
    __syncthreads();                                   // BB4

    // ---- in-place convert: u16 fixed -> bf16 (same swizzled slots) ----
    {
        const int key = (row & 7) << 4;
        #pragma unroll
        for (int c = 0; c < 4; ++c) {
            char* p = Abc + (((row << 8) + (l4 << 6) + (c << 4)) ^ key);
            u32x4 v = *(const u32x4*)p;
            #pragma unroll
            for (int k = 0; k < 4; ++k) {
                const unsigned u = v[k];
                const float flo = (float)(u & 0xFFFFu) * QI;
                const float fhi = (float)(u >> 16) * QI;
                v[k] = (unsigned)f2bf(flo) | ((unsigned)f2bf(fhi) << 16);
            }
            *(u32x4*)p = v;
        }
    }
    // (no barrier: Ab reads happen after B3; a0s complete since BB4)

    // ---- layer-2 propagate: a1 = Â @ x1, x1 built in two 64-K halves ----
    f4 accm0 = {0.f,0.f,0.f,0.f}, accm1 = {0.f,0.f,0.f,0.f};
    const int arow = (wv << 4) + l;                    // wave-exclusive Â row
    const int akey = (arow & 7) << 4;
    #pragma unroll
    for (int half = 0; half < 2; ++half) {
        {   // build x1h half: x1h[j][k] = relu(a0[64h+k]*w1[j]+b1[j])
            const int jj = tid >> 4;                   // x1T row 0..31
            const float w1j = W1[jj], b1j = b1[jj];    // L2-hot
            const int kk = (tid & 15) << 2;            // 0..60
            const fl4 av = *(const fl4*)&a0s[(half << 6) + kk];
            union { unsigned u[2]; s4v v; } P;
            P.u[0] = (unsigned)f2bf(fmaxf(fmaf(av[0], w1j, b1j), 0.f))
                   | ((unsigned)f2bf(fmaxf(fmaf(av[1], w1j, b1j), 0.f)) << 16);
            P.u[1] = (unsigned)f2bf(fmaxf(fmaf(av[2], w1j, b1j), 0.f))
                   | ((unsigned)f2bf(fmaxf(fmaf(av[3], w1j, b1j), 0.f)) << 16);
            *(s4v*)&x1h[jj * X1STRIDE + kk] = P.v;
        }
        __syncthreads();                               // B3 / B5
        #pragma unroll
        for (int ks2 = 0; ks2 < 2; ++ks2) {
            const int kloc = (ks2 << 5) + (q << 3);
            const s8 A = *(const s8*)(Abc +
                (((arow << 8) + (half << 7) + (ks2 << 6) + (q << 4)) ^ akey));
            const s8 B0 = *(const s8*)&x1h[l * X1STRIDE + kloc];
            const s8 B1 = *(const s8*)&x1h[(16 + l) * X1STRIDE + kloc];
            accm0 = __builtin_amdgcn_mfma_f32_16x16x32_bf16(A, B0, accm0, 0, 0, 0);
            accm1 = __builtin_amdgcn_mfma_f32_16x16x32_bf16(A, B1, accm1, 0, 0, 0);
        }
        if (half == 0) __syncthreads();                // B4 (x1h reads done)
    }

    // ---- a1 -> a1b (same wave, DS in-order: no barrier); Â stays intact ----
    short* a1w = &a1b[(wv << 4) * A1STRIDE];           // 16 rows x A1STRIDE
    #pragma unroll
    for (int r = 0; r < 4; ++r) {
        const int tr = (q << 2) + r;
        a1w[tr * A1STRIDE + l]      = (short)f2bf(accm0[r]);
        a1w[tr * A1STRIDE + 16 + l] = (short)f2bf(accm1[r]);
    }

    // ---- P7: x2 = relu(a1@W2+b2); s = x2@W3 (W2 frags from L2-hot global) ----
    {
        s8 Bw0, Bw1;
        #pragma unroll
        for (int j2 = 0; j2 < 8; ++j2) {
            const int krow = (q << 3) + j2;
            Bw0[j2] = (short)f2bf(W2[(krow << 5) + l]);
            Bw1[j2] = (short)f2bf(W2[(krow << 5) + 16 + l]);
        }
        const s8 A0 = *(const s8*)&a1w[l * A1STRIDE + (q << 3)];
        f4 ac20 = {0.f,0.f,0.f,0.f}, ac21 = {0.f,0.f,0.f,0.f};
        ac20 = __builtin_amdgcn_mfma_f32_16x16x32_bf16(A0, Bw0, ac20, 0, 0, 0);
        ac21 = __builtin_amdgcn_mfma_f32_16x16x32_bf16(A0, Bw1, ac21, 0, 0, 0);

        const float b2a = b2[l], b2b = b2[l + 16];     // L2-hot, loaded at use
        const float w3a = W3[l], w3b = W3[l + 16];
        #pragma unroll
        for (int r = 0; r < 4; ++r) {
            const float v0 = fmaxf(ac20[r] + b2a, 0.f);
            const float v1 = fmaxf(ac21[r] + b2b, 0.f);
            float sv = v0 * w3a + v1 * w3b;
            #pragma unroll
            for (int m = 1; m < 16; m <<= 1) sv += __shfl_xor(sv, m, 16);
            if (l == 0) sbuf[(wv << 4) + (q << 2) + r] = sv;
        }
    }
    __syncthreads();                                   // B6

    // ---- layer-3 propagate, edge-parallel in fp32: out = Â·s + b3 ----
    if (tid < NUMK) {                                  // init: bias + self term
        const float dq = degv[tid];
        a0s[tid] = b3[0] + dq * dq * sbuf[tid];        // a0s reused as outacc
    }
    __syncthreads();                                   // B7
    atomicAdd(&a0s[d0], nv0 * sbuf[s0]);
    atomicAdd(&a0s[d1], nv1 * sbuf[s1]);
    __syncthreads();                                   // B8
    if (tid < NUMK)
        out[(size_t)blockIdx.x * NUMK + tid] = a0s[tid];
}

extern "C" void kernel_launch(void* const* d_in, const int* in_sizes, int n_in,
                              void* d_out, int out_size, void* d_ws, size_t ws_size,
                              hipStream_t stream) {
    const float* Hx = (const float*)d_in[0];
    const int*   ei = (const int*)d_in[1];
    const float* W1 = (const float*)d_in[2];
    const float* b1 = (const float*)d_in[3];
    const float* W2 = (const float*)d_in[4];
    const float* b2 = (const float*)d_in[5];
    const float* W3 = (const float*)d_in[6];
    const float* b3 = (const float*)d_in[7];
    float* out = (float*)d_out;

    (void)d_ws; (void)ws_size;   // workspace untouched
    gcn_fused_kernel<<<NB, 512, 0, stream>>>(Hx, ei, W1, b1, W2, b2, W3, b3, out);
}

// Round 3
// 108.571 us; speedup vs baseline: 1.2070x; 1.0933x over previous
//
#include <hip/hip_runtime.h>
#include <hip/hip_bf16.h>

#define NB    2048
#define NUMK  128
#define NE    1024
#define HID   32
#define ROWLEN (NUMK + NE + 2)
#define X1STRIDE 72              // bf16 elems per x1T-half row (64 + 8 pad)
#define A1STRIDE 40              // bf16 elems per a1 row inside Ab span
#define QS 8192.0f               // fixed-point scale 2^13
#define QI (1.0f/8192.0f)

// R3: single kernel, dense parallel build, slimmed.
//  - Scatter RAW weights w (u16 fixed-point, packed 2/u32) into dense Â via
//    LDS atomicAdd; dup edges merge for free. deg via 2 fp32 LDS atomics.
//  - Convert pass folds dinv[d]*dinv[s]*QI normalization AND the a0 = Â·p
//    accumulation (p staged in LDS) into the u16->bf16 conversion: per u32
//    ~10 VALU (was ~17 + separate nv/a0 atomic passes). bf16 pack via
//    v_cvt_pk_bf16_f32 (inline asm, RNE).
//  - Â dead after layer-2 MFMA (layer-3 recomputes fp32 norms from degv +
//    edge regs) -> a1 overwrites Ab's own wave span (R0-style), LDS 49152 ->
//    38912 B -> 4 blocks/CU (thread cap), launch_bounds(512,8).
//  - XOR swizzle byte^=((row&7)<<4) on Â at scatter/convert/MFMA-read.
// MFMA skeleton verbatim from validated R2.

using s8    = __attribute__((ext_vector_type(8))) short;   // 8 bf16 = 16 B
using s4v   = __attribute__((ext_vector_type(4))) short;   // 4 bf16 = 8 B
using f4    = __attribute__((ext_vector_type(4))) float;
using fl4   = __attribute__((ext_vector_type(4))) float;
using u32x4 = __attribute__((ext_vector_type(4))) unsigned;

static __device__ __forceinline__ unsigned short f2bf(float f) {
    unsigned u = __float_as_uint(f);
    unsigned r = (u + 0x7fffu + ((u >> 16) & 1u)) >> 16;   // RNE
    return (unsigned short)r;
}
static __device__ __forceinline__ unsigned cvtpk(float lo, float hi) {
    unsigned r;                                            // D.lo=bf16(lo), D.hi=bf16(hi)
    asm("v_cvt_pk_bf16_f32 %0, %1, %2" : "=v"(r) : "v"(lo), "v"(hi));
    return r;
}

__global__ __launch_bounds__(512, 8) void gcn_fused_kernel(
    const float* __restrict__ Hx,
    const int*   __restrict__ ei,
    const float* __restrict__ W1, const float* __restrict__ b1,
    const float* __restrict__ W2, const float* __restrict__ b2,
    const float* __restrict__ W3, const float* __restrict__ b3,
    float* __restrict__ out)
{
    __shared__ __align__(16) short Ab[NUMK * 128];          // 32768 B (u32 alias)
    __shared__ __align__(16) short x1h[HID * X1STRIDE];     //  4608 B (p_lds overlay)
    __shared__ float degv[NUMK];                            //   512 B (deg -> dinv)
    __shared__ float a0s[NUMK];                             //   512 B (a0 -> outacc)
    __shared__ float sbuf[NUMK];                            //   512 B (layer-3 s)
    // total 38,912 B -> 4 blocks/CU (thread-capped at 4)

    const int tid = threadIdx.x;                // 0..511
    const int row = tid >> 2, l4 = tid & 3;     // 128 rows x 4 lanes
    const int wv = tid >> 6, lane = tid & 63;
    const int l = lane & 15, q = lane >> 4;
    const float* rowp = Hx + (size_t)blockIdx.x * ROWLEN;
    unsigned* Apk = (unsigned*)Ab;
    char*     Abc = (char*)Ab;
    float*    pl  = (float*)x1h;                // p staging (dead before x1 build)

    // ---- P0: edge/weight loads, zero Apk, stage p, init deg ----
    const int e0 = tid, e1 = tid + 512;
    const int s0 = ei[e0]      & (NUMK - 1);
    const int d0 = ei[NE + e0] & (NUMK - 1);
    const int s1 = ei[e1]      & (NUMK - 1);
    const int d1 = ei[NE + e1] & (NUMK - 1);
    const float w0 = rowp[NUMK + e0];
    const float w1 = rowp[NUMK + e1];

    {
        const u32x4 z4 = {0u, 0u, 0u, 0u};
        #pragma unroll
        for (int c = 0; c < 4; ++c)
            *(u32x4*)&Apk[(tid << 2) + (c << 11)] = z4;
    }
    if (tid < NUMK) { degv[tid] = 1.0f; pl[tid] = rowp[tid]; }
    __syncthreads();                                   // BB1

    // ---- P1: scatter raw w (packed u16 fixed) + deg (fp32) ----
    {
        const unsigned q0 = __float2uint_rn(w0 * QS);
        const unsigned q1 = __float2uint_rn(w1 * QS);
        atomicAdd(&Apk[(((unsigned)d0 << 6) + ((unsigned)s0 >> 1)) ^ (((unsigned)d0 & 7u) << 2)],
                  q0 << (((unsigned)s0 & 1u) << 4));
        atomicAdd(&Apk[(((unsigned)d1 << 6) + ((unsigned)s1 >> 1)) ^ (((unsigned)d1 & 7u) << 2)],
                  q1 << (((unsigned)s1 & 1u) << 4));
        atomicAdd(&degv[d0], w0);
        atomicAdd(&degv[d1], w1);
        if (tid < NUMK)                                // self-loop, w = 1.0
            atomicAdd(&Apk[(((unsigned)tid << 6) + ((unsigned)tid >> 1)) ^ (((unsigned)tid & 7u) << 2)],
                      8192u << (((unsigned)tid & 1u) << 4));
    }
    __syncthreads();                                   // BB2
    if (tid < NUMK) degv[tid] = rsqrtf(degv[tid]);     // deg >= 1 always
    __syncthreads();                                   // BB3

    // ---- P3: convert u16 -> bf16 with folded norm; a0 accumulated in-pass ----
    {
        const float dr = degv[row];
        const float sc = dr * QI;
        const unsigned key = ((unsigned)row & 7u) << 2;    // u32-index XOR key
        float acc = 0.f;
        #pragma unroll
        for (int c = 0; c < 4; ++c) {
            const int lw = (l4 << 4) + (c << 2);           // logical wcol base
            unsigned* ap = &Apk[(((unsigned)row << 6) + (unsigned)lw) ^ key];
            u32x4 v = *(const u32x4*)ap;
            const int cb = lw << 1;                        // logical col base
            const fl4 dv0 = *(const fl4*)&degv[cb];
            const fl4 dv1 = *(const fl4*)&degv[cb + 4];
            const fl4 pv0 = *(const fl4*)&pl[cb];
            const fl4 pv1 = *(const fl4*)&pl[cb + 4];
            #pragma unroll
            for (int j = 0; j < 4; ++j) {
                const unsigned u = v[j];
                const float dlo = (j < 2) ? dv0[2 * j]     : dv1[2 * j - 4];
                const float dhi = (j < 2) ? dv0[2 * j + 1] : dv1[2 * j - 3];
                const float plo = (j < 2) ? pv0[2 * j]     : pv1[2 * j - 4];
                const float phi = (j < 2) ? pv0[2 * j + 1] : pv1[2 * j - 3];
                const float nlo = (float)(u & 0xFFFFu) * sc * dlo;
                const float nhi = (float)(u >> 16)     * sc * dhi;
                acc = fmaf(nlo, plo, fmaf(nhi, phi, acc));
                v[j] = cvtpk(nlo, nhi);
            }
            *(u32x4*)ap = v;
        }
        acc += __shfl_xor(acc, 1, 4);
        acc += __shfl_xor(acc, 2, 4);
        if (l4 == 0) a0s[row] = acc;
    }
    __syncthreads();                                   // B2

    // ---- layer-2 propagate: a1 = Â @ x1, x1 built in two 64-K halves ----
    f4 accm0 = {0.f,0.f,0.f,0.f}, accm1 = {0.f,0.f,0.f,0.f};
    const int arow = (wv << 4) + l;                    // wave-exclusive Â row
    const int akey = (arow & 7) << 4;                  // byte XOR key
    #pragma unroll
    for (int half = 0; half < 2; ++half) {
        {   // build x1h half: x1h[j][k] = relu(a0[64h+k]*w1[j]+b1[j])
            const int jj = tid >> 4;                   // x1T row 0..31
            const float w1j = W1[jj], b1j = b1[jj];    // L2-hot
            const int kk = (tid & 15) << 2;            // 0..60
            const fl4 av = *(const fl4*)&a0s[(half << 6) + kk];
            union { unsigned u[2]; s4v v; } P;
            P.u[0] = cvtpk(fmaxf(fmaf(av[0], w1j, b1j), 0.f),
                           fmaxf(fmaf(av[1], w1j, b1j), 0.f));
            P.u[1] = cvtpk(fmaxf(fmaf(av[2], w1j, b1j), 0.f),
                           fmaxf(fmaf(av[3], w1j, b1j), 0.f));
            *(s4v*)&x1h[jj * X1STRIDE + kk] = P.v;
        }
        __syncthreads();                               // B3 / B5
        #pragma unroll
        for (int ks2 = 0; ks2 < 2; ++ks2) {
            const int kloc = (ks2 << 5) + (q << 3);
            const s8 A = *(const s8*)(Abc +
                (((arow << 8) + (half << 7) + (ks2 << 6) + (q << 4)) ^ akey));
            const s8 B0 = *(const s8*)&x1h[l * X1STRIDE + kloc];
            const s8 B1 = *(const s8*)&x1h[(16 + l) * X1STRIDE + kloc];
            accm0 = __builtin_amdgcn_mfma_f32_16x16x32_bf16(A, B0, accm0, 0, 0, 0);
            accm1 = __builtin_amdgcn_mfma_f32_16x16x32_bf16(A, B1, accm1, 0, 0, 0);
        }
        if (half == 0) __syncthreads();                // B4 (x1h reads done)
    }

    // ---- a1 -> own Â span (same wave, DS in-order: no barrier; Â now dead) ----
    short* a1w = &Ab[(wv << 4) << 7];                  // 16 Ab rows of this wave
    #pragma unroll
    for (int r = 0; r < 4; ++r) {
        const int tr = (q << 2) + r;
        a1w[tr * A1STRIDE + l]      = (short)f2bf(accm0[r]);
        a1w[tr * A1STRIDE + 16 + l] = (short)f2bf(accm1[r]);
    }

    // ---- P7: x2 = relu(a1@W2+b2); s = x2@W3 (W2 frags from L2-hot global) ----
    {
        union { unsigned u[4]; s8 v; } BW0, BW1;
        #pragma unroll
        for (int j2 = 0; j2 < 4; ++j2) {
            const int krow = (q << 3) + (j2 << 1);
            BW0.u[j2] = cvtpk(W2[(krow << 5) + l],      W2[((krow + 1) << 5) + l]);
            BW1.u[j2] = cvtpk(W2[(krow << 5) + 16 + l], W2[((krow + 1) << 5) + 16 + l]);
        }
        const s8 A0 = *(const s8*)&a1w[l * A1STRIDE + (q << 3)];
        f4 ac20 = {0.f,0.f,0.f,0.f}, ac21 = {0.f,0.f,0.f,0.f};
        ac20 = __builtin_amdgcn_mfma_f32_16x16x32_bf16(A0, BW0.v, ac20, 0, 0, 0);
        ac21 = __builtin_amdgcn_mfma_f32_16x16x32_bf16(A0, BW1.v, ac21, 0, 0, 0);

        const float b2a = b2[l], b2b = b2[l + 16];     // L2-hot, loaded at use
        const float w3a = W3[l], w3b = W3[l + 16];
        #pragma unroll
        for (int r = 0; r < 4; ++r) {
            const float v0 = fmaxf(ac20[r] + b2a, 0.f);
            const float v1 = fmaxf(ac21[r] + b2b, 0.f);
            float sv = v0 * w3a + v1 * w3b;
            #pragma unroll
            for (int m = 1; m < 16; m <<= 1) sv += __shfl_xor(sv, m, 16);
            if (l == 0) sbuf[(wv << 4) + (q << 2) + r] = sv;
        }
    }
    __syncthreads();                                   // B6

    // ---- layer-3 propagate, edge-parallel fp32: out = Â·s + b3 ----
    if (tid < NUMK) {                                  // init: bias + self term
        const float dq = degv[tid];
        a0s[tid] = b3[0] + dq * dq * sbuf[tid];        // a0s reused as outacc
    }
    __syncthreads();                                   // B7
    {
        const float nv0 = degv[s0] * w0 * degv[d0];    // exact fp32 norms
        const float nv1 = degv[s1] * w1 * degv[d1];
        atomicAdd(&a0s[d0], nv0 * sbuf[s0]);
        atomicAdd(&a0s[d1], nv1 * sbuf[s1]);
    }
    __syncthreads();                                   // B8
    if (tid < NUMK)
        out[(size_t)blockIdx.x * NUMK + tid] = a0s[tid];
}

extern "C" void kernel_launch(void* const* d_in, const int* in_sizes, int n_in,
                              void* d_out, int out_size, void* d_ws, size_t ws_size,
                              hipStream_t stream) {
    const float* Hx = (const float*)d_in[0];
    const int*   ei = (const int*)d_in[1];
    const float* W1 = (const float*)d_in[2];
    const float* b1 = (const float*)d_in[3];
    const float* W2 = (const float*)d_in[4];
    const float* b2 = (const float*)d_in[5];
    const float* W3 = (const float*)d_in[6];
    const float* b3 = (const float*)d_in[7];
    float* out = (float*)d_out;

    (void)d_ws; (void)ws_size;
    gcn_fused_kernel<<<NB, 512, 0, stream>>>(Hx, ei, W1, b1, W2, b2, W3, b3, out);
}